// Round 1
// baseline (179.035 us; speedup 1.0000x reference)
//
#include <hip/hip_runtime.h>
#include <stdint.h>

typedef __attribute__((ext_vector_type(8))) __bf16 bf16x8;
typedef __attribute__((ext_vector_type(4))) __bf16 bf16x4;
typedef __attribute__((ext_vector_type(4))) float f32x4;

// ---------------- gates: softmax(x @ W_aux^T + b_aux) ----------------
// one wave per row, 4 rows/block, grid 1024
__global__ __launch_bounds__(256) void k_gates(const float* __restrict__ x,
                                               const float* __restrict__ Waux,
                                               const float* __restrict__ baux,
                                               float* __restrict__ gates) {
  const int wave = threadIdx.x >> 6;
  const int lane = threadIdx.x & 63;
  const int row = blockIdx.x * 4 + wave;
  const float4* xr = (const float4*)(x + (size_t)row * 512);
  const float4* w0 = (const float4*)(Waux);
  const float4* w1 = (const float4*)(Waux + 512);
  float p0 = 0.f, p1 = 0.f;
  for (int c = lane; c < 128; c += 64) {
    float4 xv = xr[c];
    float4 a = w0[c], b = w1[c];
    p0 += xv.x * a.x + xv.y * a.y + xv.z * a.z + xv.w * a.w;
    p1 += xv.x * b.x + xv.y * b.y + xv.z * b.z + xv.w * b.w;
  }
  for (int off = 32; off; off >>= 1) {
    p0 += __shfl_down(p0, off, 64);
    p1 += __shfl_down(p1, off, 64);
  }
  if (lane == 0) {
    p0 += baux[0]; p1 += baux[1];
    float m = fmaxf(p0, p1);
    float e0 = __expf(p0 - m), e1 = __expf(p1 - m);
    float inv = 1.f / (e0 + e1);
    gates[row * 2 + 0] = e0 * inv;
    gates[row * 2 + 1] = e1 * inv;
  }
}

// ---------------- outs GEMM: C[m][n] = sum_k x[m][k] * Wflat[n][k] + bias[n] ----
// M=4096, N=512, K=512. 128x128 tiles, 4 waves of 64x64, mfma 16x16x32 bf16.
// Writes totalbf[l*4096 + m][o] where n = l*256 + o.
__global__ __launch_bounds__(256) void k_outs(const float* __restrict__ x,
                                              const float* __restrict__ W,
                                              const float* __restrict__ bias,
                                              __bf16* __restrict__ totalbf) {
  __shared__ __bf16 As[128][64];
  __shared__ __bf16 Bs[128][64];
  const int bj = blockIdx.x;   // 0..3  (N tiles)
  const int bi = blockIdx.y;   // 0..31 (M tiles)
  const int t = threadIdx.x;
  const int wid = t >> 6, lane = t & 63;
  const int wr = wid >> 1, wc = wid & 1;
  const int n16 = lane & 15, q = lane >> 4;

  f32x4 acc[4][4];
  f32x4 zero = {0.f, 0.f, 0.f, 0.f};
  for (int i = 0; i < 4; ++i)
    for (int j = 0; j < 4; ++j) acc[i][j] = zero;

  const int arow0 = bi * 128;
  const int brow0 = bj * 128;

  for (int kc = 0; kc < 512; kc += 64) {
    for (int p = 0; p < 8; ++p) {
      int e = p * 256 + t;            // 0..2047
      int row = e >> 4;               // 0..127
      int c4 = (e & 15) << 2;         // 0..60
      float4 va = *(const float4*)(x + (size_t)(arow0 + row) * 512 + kc + c4);
      bf16x4 ba = {(__bf16)va.x, (__bf16)va.y, (__bf16)va.z, (__bf16)va.w};
      *(bf16x4*)&As[row][c4] = ba;
      float4 vb = *(const float4*)(W + (size_t)(brow0 + row) * 512 + kc + c4);
      bf16x4 bb = {(__bf16)vb.x, (__bf16)vb.y, (__bf16)vb.z, (__bf16)vb.w};
      *(bf16x4*)&Bs[row][c4] = bb;
    }
    __syncthreads();
    for (int ks = 0; ks < 2; ++ks) {
      bf16x8 af[4], bfr[4];
      for (int f = 0; f < 4; ++f) {
        af[f]  = *(const bf16x8*)&As[wr * 64 + f * 16 + n16][ks * 32 + q * 8];
        bfr[f] = *(const bf16x8*)&Bs[wc * 64 + f * 16 + n16][ks * 32 + q * 8];
      }
      for (int fr = 0; fr < 4; ++fr)
        for (int fc = 0; fc < 4; ++fc)
          acc[fr][fc] = __builtin_amdgcn_mfma_f32_16x16x32_bf16(af[fr], bfr[fc], acc[fr][fc], 0, 0, 0);
    }
    __syncthreads();
  }

  // epilogue: +bias, write bf16 total (row = l*4096 + m, col = o)
  for (int fc = 0; fc < 4; ++fc) {
    int n_g = bj * 128 + wc * 64 + fc * 16 + n16;   // 0..511
    float bv = bias[n_g];
    int l = n_g >> 8, o = n_g & 255;
    for (int fr = 0; fr < 4; ++fr) {
      for (int r = 0; r < 4; ++r) {
        int m_g = bi * 128 + wr * 64 + fr * 16 + q * 4 + r;
        float v = acc[fr][fc][r] + bv;
        totalbf[(size_t)(l * 4096 + m_g) * 256 + o] = (__bf16)v;
      }
    }
  }
}

// ---------------- sq[i] = sum_k total[i][k]^2 ; colsum[k] = sum_i total[i][k] ----
// 256 blocks x 256 threads; block handles 32 rows (wave w: rows blk*32+w*8..+8)
__global__ __launch_bounds__(256) void k_sq(const __bf16* __restrict__ tot,
                                            float* __restrict__ sq,
                                            float* __restrict__ colsum) {
  __shared__ float lcol[4][256];
  const int t = threadIdx.x;
  const int wave = t >> 6, lane = t & 63;
  float c0 = 0.f, c1 = 0.f, c2 = 0.f, c3 = 0.f;
  for (int it = 0; it < 8; ++it) {
    int row = blockIdx.x * 32 + wave * 8 + it;
    bf16x4 v = *(const bf16x4*)(tot + (size_t)row * 256 + lane * 4);
    float f0 = v[0], f1 = v[1], f2 = v[2], f3 = v[3];
    float s = f0 * f0 + f1 * f1 + f2 * f2 + f3 * f3;
    for (int off = 32; off; off >>= 1) s += __shfl_down(s, off, 64);
    if (lane == 0) sq[row] = s;
    c0 += f0; c1 += f1; c2 += f2; c3 += f3;
  }
  lcol[wave][lane * 4 + 0] = c0;
  lcol[wave][lane * 4 + 1] = c1;
  lcol[wave][lane * 4 + 2] = c2;
  lcol[wave][lane * 4 + 3] = c3;
  __syncthreads();
  float s2 = lcol[0][t] + lcol[1][t] + lcol[2][t] + lcol[3][t];
  atomicAdd(&colsum[t], s2);
}

// ---------------- bandwidth: sum(dist) = 2n*sum(sq) - 2*||colsum||^2 ----------
__global__ __launch_bounds__(256) void k_bw(const float* __restrict__ sq,
                                            const float* __restrict__ colsum,
                                            float* __restrict__ scal) {
  __shared__ float red[256];
  const int t = threadIdx.x;
  float s = 0.f;
  for (int i = t; i < 8192; i += 256) s += sq[i];
  red[t] = s;
  __syncthreads();
  for (int off = 128; off; off >>= 1) { if (t < off) red[t] += red[t + off]; __syncthreads(); }
  float sumsq = red[0];
  __syncthreads();
  float c = colsum[t];
  red[t] = c * c;
  __syncthreads();
  for (int off = 128; off; off >>= 1) { if (t < off) red[t] += red[t + off]; __syncthreads(); }
  if (t == 0) {
    double sumdist = 2.0 * 8192.0 * (double)sumsq - 2.0 * (double)red[0];
    double bw = sumdist / (8192.0 * 8192.0 - 8192.0) / 4.0;   // / KERNEL_MUL^(5//2)
    scal[1] = (float)(1.4426950408889634 / (bw * 16.0));      // g4 * log2(e)
    scal[2] = (float)bw;
  }
}

// ---------------- combine[b][o] = g0*outs0 + g1*outs1 ------------------------
__global__ __launch_bounds__(256) void k_combine(const __bf16* __restrict__ tot,
                                                 const float* __restrict__ gates,
                                                 float* __restrict__ out) {
  int idx = blockIdx.x * 256 + threadIdx.x;   // 0..262143, 4 outputs each
  int b = idx >> 6;
  int oc = (idx & 63) * 4;
  float g0 = gates[b * 2], g1 = gates[b * 2 + 1];
  bf16x4 v0 = *(const bf16x4*)(tot + (size_t)b * 256 + oc);
  bf16x4 v1 = *(const bf16x4*)(tot + (size_t)(4096 + b) * 256 + oc);
  float4 r;
  r.x = g0 * (float)v0[0] + g1 * (float)v1[0];
  r.y = g0 * (float)v0[1] + g1 * (float)v1[1];
  r.z = g0 * (float)v0[2] + g1 * (float)v1[2];
  r.w = g0 * (float)v0[3] + g1 * (float)v1[3];
  *(float4*)(out + (size_t)b * 256 + oc) = r;
}

// ---------------- Gram tiles + fused multi-bandwidth kernel sum ---------------
// tile (ti,tj), ti<=tj only (symmetric), 128x128 per block, K=256.
// dist = sq[i]+sq[j]-2*dot ; ksum = u+u^2+u^4+u^8+u^16, u = exp(-dist*g4)
// sign uniform per tile; weight 2 off-diagonal, 1 on diagonal.
__global__ __launch_bounds__(256) void k_gram(const __bf16* __restrict__ tot,
                                              const float* __restrict__ sq,
                                              const float* __restrict__ scal,
                                              float* __restrict__ Ssum) {
  const int tj = blockIdx.x, ti = blockIdx.y;
  if (tj < ti) return;
  __shared__ __bf16 As[128][64];
  __shared__ __bf16 Bs[128][64];
  __shared__ float sqi[128], sqj[128];
  __shared__ float wred[4];
  const int t = threadIdx.x;
  const int wid = t >> 6, lane = t & 63;
  const int wr = wid >> 1, wc = wid & 1;
  const int n16 = lane & 15, q = lane >> 4;

  if (t < 128) sqi[t] = sq[ti * 128 + t];
  else         sqj[t - 128] = sq[tj * 128 + (t - 128)];

  f32x4 acc[4][4];
  f32x4 zero = {0.f, 0.f, 0.f, 0.f};
  for (int i = 0; i < 4; ++i)
    for (int j = 0; j < 4; ++j) acc[i][j] = zero;

  const int arow0 = ti * 128, brow0 = tj * 128;
  for (int kc = 0; kc < 256; kc += 64) {
    for (int p = 0; p < 4; ++p) {
      int e = p * 256 + t;          // 0..1023
      int row = e >> 3;             // 0..127
      int c8 = (e & 7) << 3;        // 0..56
      *(uint4*)&As[row][c8] = *(const uint4*)(tot + (size_t)(arow0 + row) * 256 + kc + c8);
      *(uint4*)&Bs[row][c8] = *(const uint4*)(tot + (size_t)(brow0 + row) * 256 + kc + c8);
    }
    __syncthreads();
    for (int ks = 0; ks < 2; ++ks) {
      bf16x8 af[4], bfr[4];
      for (int f = 0; f < 4; ++f) {
        af[f]  = *(const bf16x8*)&As[wr * 64 + f * 16 + n16][ks * 32 + q * 8];
        bfr[f] = *(const bf16x8*)&Bs[wc * 64 + f * 16 + n16][ks * 32 + q * 8];
      }
      for (int fr = 0; fr < 4; ++fr)
        for (int fc = 0; fc < 4; ++fc)
          acc[fr][fc] = __builtin_amdgcn_mfma_f32_16x16x32_bf16(af[fr], bfr[fc], acc[fr][fc], 0, 0, 0);
    }
    __syncthreads();
  }

  const float g = scal[1];
  float lsum = 0.f;
  for (int fr = 0; fr < 4; ++fr) {
    for (int r = 0; r < 4; ++r) {
      float si = sqi[wr * 64 + fr * 16 + q * 4 + r];
      for (int fc = 0; fc < 4; ++fc) {
        float sj = sqj[wc * 64 + fc * 16 + n16];
        float dist = si + sj - 2.f * acc[fr][fc][r];
        float e = exp2f(-dist * g);
        float e2 = e * e, e4 = e2 * e2, e8 = e4 * e4, e16 = e8 * e8;
        lsum += e + e2 + e4 + e8 + e16;
      }
    }
  }
  for (int off = 32; off; off >>= 1) lsum += __shfl_down(lsum, off, 64);
  if (lane == 0) wred[wid] = lsum;
  __syncthreads();
  if (t == 0) {
    float blocksum = wred[0] + wred[1] + wred[2] + wred[3];
    float sgn = ((ti < 32) == (tj < 32)) ? 1.f : -1.f;
    float wgt = (ti == tj) ? sgn : 2.f * sgn;
    atomicAdd(Ssum, wgt * blocksum);
  }
}

// ---------------- final scalar: -mean = -S / B^2 ------------------------------
__global__ void k_final(const float* __restrict__ scal, float* __restrict__ out) {
  out[1048576] = -(scal[0] / 16777216.0f);
}

extern "C" void kernel_launch(void* const* d_in, const int* in_sizes, int n_in,
                              void* d_out, int out_size, void* d_ws, size_t ws_size,
                              hipStream_t stream) {
  const float* x    = (const float*)d_in[0];
  const float* Waux = (const float*)d_in[1];
  const float* baux = (const float*)d_in[2];
  const float* W    = (const float*)d_in[3];
  const float* bias = (const float*)d_in[4];
  float* out = (float*)d_out;

  char* ws = (char*)d_ws;
  __bf16* totalbf = (__bf16*)ws;                    // 8192*256*2 = 4,194,304 B
  float* sq      = (float*)(ws + 4194304);          // 8192 f32
  float* colsum  = (float*)(ws + 4227072);          // 256 f32
  float* scal    = (float*)(ws + 4228096);          // [0]=Ssum [1]=g4l2 [2]=bw
  float* gates   = (float*)(ws + 4228160);          // 4096*2 f32

  // zero the atomic accumulators (colsum + scalars); ws is poisoned each launch
  hipMemsetAsync(ws + 4227072, 0, 1024 + 64, stream);

  k_gates<<<1024, 256, 0, stream>>>(x, Waux, baux, gates);
  k_outs<<<dim3(4, 32), 256, 0, stream>>>(x, W, bias, totalbf);
  k_sq<<<256, 256, 0, stream>>>(totalbf, sq, colsum);
  k_bw<<<1, 256, 0, stream>>>(sq, colsum, scal);
  k_combine<<<1024, 256, 0, stream>>>(totalbf, gates, out);
  k_gram<<<dim3(64, 64), 256, 0, stream>>>(totalbf, sq, scal, scal);
  k_final<<<1, 1, 0, stream>>>(scal, out);
}